// Round 2
// baseline (449.942 us; speedup 1.0000x reference)
//
#include <hip/hip_runtime.h>
#include <hip/hip_bf16.h>

#define N 8192
#define FIN 512
#define FOUT 64
#define ALPHA 0.2f

typedef __bf16 bf16x8 __attribute__((ext_vector_type(8)));
typedef __bf16 bf16x4 __attribute__((ext_vector_type(4)));
typedef float f32x4 __attribute__((ext_vector_type(4)));
typedef int i32x4 __attribute__((ext_vector_type(4)));

// ---- workspace layout (bytes) ----
// [0,64)            : Mkey (ordered-uint global max of f_dst)
// [64, 32832)       : lsum (N floats)
// [32832, 65600)    : f_src (N floats)
// [65600, 98368)    : f_dst (N floats)
// [98368, 163904)   : WtG  (bf16 [FOUT][FIN], W transposed)
// [163904, 1212480) : hT   (bf16 [FOUT][N], h transposed)

__device__ __forceinline__ unsigned enc_f(float x) {
    unsigned u = __float_as_uint(x);
    return (u & 0x80000000u) ? ~u : (u | 0x80000000u);
}
__device__ __forceinline__ float dec_f(unsigned u) {
    return (u & 0x80000000u) ? __uint_as_float(u & 0x7FFFFFFFu) : __uint_as_float(~u);
}

// ---------- k_wt: WtG[f][k] = bf16(W[k][f]) --------------------------------
__global__ __launch_bounds__(64) void k_wt(const float* __restrict__ W,
                                           __bf16* __restrict__ WtG) {
    const int g = blockIdx.x * 64 + threadIdx.x;  // 0..4095
    const int k = g >> 3;
    const int f0 = (g & 7) * 8;
    const float4 w0 = *(const float4*)(W + (size_t)k * FOUT + f0);
    const float4 w1 = *(const float4*)(W + (size_t)k * FOUT + f0 + 4);
    WtG[(size_t)(f0 + 0) * FIN + k] = (__bf16)w0.x;
    WtG[(size_t)(f0 + 1) * FIN + k] = (__bf16)w0.y;
    WtG[(size_t)(f0 + 2) * FIN + k] = (__bf16)w0.z;
    WtG[(size_t)(f0 + 3) * FIN + k] = (__bf16)w0.w;
    WtG[(size_t)(f0 + 4) * FIN + k] = (__bf16)w1.x;
    WtG[(size_t)(f0 + 5) * FIN + k] = (__bf16)w1.y;
    WtG[(size_t)(f0 + 6) * FIN + k] = (__bf16)w1.z;
    WtG[(size_t)(f0 + 7) * FIN + k] = (__bf16)w1.w;
}

// ---------- k12: h=in@W (MFMA) -> f_src/f_dst/Mkey + hT (fused) ------------
// 1 wave per block, 16 rows; 512 blocks.
__global__ __launch_bounds__(64) void k12(const float* __restrict__ in,
                                          const __bf16* __restrict__ WtG,
                                          const float* __restrict__ a,
                                          float* __restrict__ f_src,
                                          float* __restrict__ f_dst,
                                          unsigned* __restrict__ Mkey,
                                          __bf16* __restrict__ hT) {
    __shared__ __bf16 tb[64][16];
    const int lane = threadIdx.x;
    const int m = lane & 15, quad = lane >> 4;
    const int i0 = blockIdx.x * 16;

    f32x4 acc[4];
#pragma unroll
    for (int t = 0; t < 4; ++t) acc[t] = (f32x4){0.f, 0.f, 0.f, 0.f};

    const float* arow = in + (size_t)(i0 + m) * FIN + quad * 8;
    for (int k0 = 0; k0 < FIN; k0 += 32) {
        const float4 x0 = *(const float4*)(arow + k0);
        const float4 x1 = *(const float4*)(arow + k0 + 4);
        bf16x8 af;
        af[0] = (__bf16)x0.x; af[1] = (__bf16)x0.y; af[2] = (__bf16)x0.z; af[3] = (__bf16)x0.w;
        af[4] = (__bf16)x1.x; af[5] = (__bf16)x1.y; af[6] = (__bf16)x1.z; af[7] = (__bf16)x1.w;
#pragma unroll
        for (int t = 0; t < 4; ++t) {
            const bf16x8 bf = *(const bf16x8*)(WtG + (size_t)(t * 16 + m) * FIN + k0 + quad * 8);
            acc[t] = __builtin_amdgcn_mfma_f32_16x16x32_bf16(af, bf, acc[t], 0, 0, 0);
        }
    }
    // f_src / f_dst: dot rows with a1/a2, reduce across the 16 m-lanes of each quad
    float s1[4], s2[4];
#pragma unroll
    for (int r = 0; r < 4; ++r) { s1[r] = 0.f; s2[r] = 0.f; }
#pragma unroll
    for (int t = 0; t < 4; ++t) {
        const float a1 = a[t * 16 + m], a2 = a[64 + t * 16 + m];
#pragma unroll
        for (int r = 0; r < 4; ++r) {
            s1[r] += acc[t][r] * a1;
            s2[r] += acc[t][r] * a2;
        }
    }
#pragma unroll
    for (int off = 1; off <= 8; off <<= 1)
#pragma unroll
        for (int r = 0; r < 4; ++r) {
            s1[r] += __shfl_xor(s1[r], off);
            s2[r] += __shfl_xor(s2[r], off);
        }
    float lm = -1e30f;
    if (m == 0) {
#pragma unroll
        for (int r = 0; r < 4; ++r) {
            f_src[i0 + quad * 4 + r] = s1[r];
            f_dst[i0 + quad * 4 + r] = s2[r];
            lm = fmaxf(lm, s2[r]);
        }
    }
    lm = fmaxf(lm, __shfl_xor(lm, 16));
    lm = fmaxf(lm, __shfl_xor(lm, 32));
    if (lane == 0) atomicMax(Mkey, enc_f(lm));

    // hT via LDS transpose, coalesced 16B stores
#pragma unroll
    for (int t = 0; t < 4; ++t)
#pragma unroll
        for (int r = 0; r < 4; ++r) tb[t * 16 + m][quad * 4 + r] = (__bf16)acc[t][r];
    __syncthreads();
    {
        const int f = lane;
        const bf16x8 v0 = *(const bf16x8*)&tb[f][0];
        const bf16x8 v1 = *(const bf16x8*)&tb[f][8];
        *(bf16x8*)(hT + (size_t)f * N + i0) = v0;
        *(bf16x8*)(hT + (size_t)f * N + i0 + 8) = v1;
    }
}

// ---------- k3: fused mask+softmax-weight+PV ------------------------------
// Coalesced adj loads (1 row x 1KB per instr, 16-deep), per-wave swizzled
// LDS tile for the MFMA A-fragment, B-fragments direct from L1/L2-hot hT.
__global__ __launch_bounds__(256, 4) void k3_attn(const int* __restrict__ adj,
                                                  const float* __restrict__ f_src,
                                                  const float* __restrict__ fdstG,
                                                  const unsigned* __restrict__ Mkey,
                                                  const __bf16* __restrict__ hT,
                                                  float* __restrict__ num,
                                                  float* __restrict__ lsum) {
    __shared__ float sfd[1024];          // f_dst slice for this j-stripe (4 KB)
    __shared__ __bf16 wl[4][16][256];    // per-wave P-weight tile, XOR-swizzled (32 KB)
    const int tid = threadIdx.x;
    const int wv = tid >> 6, lane = tid & 63;
    const int m = lane & 15, quad = lane >> 4;
    const int i0 = __builtin_amdgcn_readfirstlane(blockIdx.x * 64 + wv * 16);
    const int jb = blockIdx.y * 1024;
    const float LOG2E = 1.44269504088896f;

    // stage f_dst[jb..jb+1024) cooperatively — the only block barrier
    *(f32x4*)&sfd[tid * 4] = *(const f32x4*)(fdstG + jb + tid * 4);
    __syncthreads();

    const float M = dec_f(*Mkey);
    float fsr[16], shl[16];  // wave-uniform per-row src-term and shift*LOG2E
#pragma unroll
    for (int r = 0; r < 16; ++r) {
        const float fs = f_src[i0 + r];
        const float t0 = fs + M;
        fsr[r] = fs;
        shl[r] = fmaxf(t0, ALPHA * t0) * LOG2E;  // leaky(fs + max f_dst) * log2(e)
    }

    f32x4 acc[4];
#pragma unroll
    for (int t = 0; t < 4; ++t) acc[t] = (f32x4){0.f, 0.f, 0.f, 0.f};
    f32x4 accl = (f32x4){0.f, 0.f, 0.f, 0.f};

    bf16x8 bones;  // ones-column B: row-sums for the denominator
#pragma unroll
    for (int jj = 0; jj < 8; ++jj) bones[jj] = (__bf16)(m == 0 ? 1.0f : 0.0f);

    const int* ap = adj + (size_t)i0 * N + jb + lane * 4;

    for (int jt = 0; jt < 1024; jt += 256) {
        // ---- A) coalesced adj loads: 16 rows x 1KB contiguous, 16 in flight
        i32x4 adjv[16];
#pragma unroll
        for (int r = 0; r < 16; ++r)
            adjv[r] = __builtin_nontemporal_load((const i32x4*)(ap + (size_t)r * N + jt));

        const f32x4 fd = *(const f32x4*)&sfd[jt + lane * 4];  // lane's 4 cols, reused for all rows

        // ---- B) exp-weights -> bf16 -> swizzled per-wave LDS tile
#pragma unroll
        for (int r = 0; r < 16; ++r) {
            bf16x4 wb;
#pragma unroll
            for (int c = 0; c < 4; ++c) {
                float e = fsr[r] + fd[c];
                e = fmaxf(e, ALPHA * e);
                const float ex = __builtin_amdgcn_exp2f(e * LOG2E - shl[r]);
                wb[c] = (__bf16)(adjv[r][c] > 0 ? ex : 0.f);
            }
            *(bf16x4*)&wl[wv][r][(lane * 4) ^ ((r & 7) << 3)] = wb;
        }

        // ---- C) MFMA: A-frag from wl (swizzled read), B-frag direct from hT
#pragma unroll
        for (int jj0 = 0; jj0 < 256; jj0 += 64) {
#pragma unroll
            for (int u = 0; u < 2; ++u) {
                const int cb = jj0 + u * 32 + quad * 8;
                const bf16x8 af = *(const bf16x8*)&wl[wv][m][cb ^ ((m & 7) << 3)];
#pragma unroll
                for (int t = 0; t < 4; ++t) {
                    const bf16x8 bfr =
                        *(const bf16x8*)(hT + (size_t)(t * 16 + m) * N + jb + jt + cb);
                    acc[t] = __builtin_amdgcn_mfma_f32_16x16x32_bf16(af, bfr, acc[t], 0, 0, 0);
                }
                accl = __builtin_amdgcn_mfma_f32_16x16x32_bf16(af, bones, accl, 0, 0, 0);
            }
        }
    }
    // epilogue: C/D col=lane&15, row=quad*4+reg
#pragma unroll
    for (int t = 0; t < 4; ++t)
#pragma unroll
        for (int r = 0; r < 4; ++r)
            atomicAdd(&num[(size_t)(i0 + quad * 4 + r) * FOUT + t * 16 + m], acc[t][r]);
    if (m == 0) {
#pragma unroll
        for (int r = 0; r < 4; ++r) atomicAdd(&lsum[i0 + quad * 4 + r], accl[r]);
    }
}

// ---------- k4: out = leaky(num / lsum, 0.01) ------------------------------
__global__ __launch_bounds__(256) void k4_norm(float* __restrict__ out,
                                               const float* __restrict__ lsum) {
    const int idx = blockIdx.x * 256 + threadIdx.x;
    const float l = lsum[idx >> 6];
    const float v = out[idx] / (l > 0.f ? l : 1.f);
    out[idx] = v > 0.f ? v : 0.01f * v;
}

extern "C" void kernel_launch(void* const* d_in, const int* in_sizes, int n_in,
                              void* d_out, int out_size, void* d_ws, size_t ws_size,
                              hipStream_t stream) {
    const float* in = (const float*)d_in[0];
    const int* adj = (const int*)d_in[1];
    const float* W = (const float*)d_in[2];
    const float* a = (const float*)d_in[3];
    float* out = (float*)d_out;

    char* ws = (char*)d_ws;
    unsigned* Mkey = (unsigned*)ws;
    float* lsum = (float*)(ws + 64);
    float* f_src = (float*)(ws + 32832);
    float* f_dst = (float*)(ws + 65600);
    __bf16* WtG = (__bf16*)(ws + 98368);
    __bf16* hT = (__bf16*)(ws + 163904);

    hipMemsetAsync(ws, 0, 64 + N * 4, stream);                      // Mkey + lsum
    hipMemsetAsync(d_out, 0, (size_t)N * FOUT * sizeof(float), stream);  // num

    k_wt<<<64, 64, 0, stream>>>(W, WtG);
    k12<<<N / 16, 64, 0, stream>>>(in, WtG, a, f_src, f_dst, Mkey, hT);

    dim3 g3(N / 64, 8);
    k3_attn<<<g3, 256, 0, stream>>>(adj, f_src, f_dst, Mkey, hT, out, lsum);
    k4_norm<<<(N * FOUT) / 256, 256, 0, stream>>>(out, lsum);
}

// Round 3
// 397.260 us; speedup vs baseline: 1.1326x; 1.1326x over previous
//
#include <hip/hip_runtime.h>
#include <hip/hip_bf16.h>

#define N 8192
#define FIN 512
#define FOUT 64
#define ALPHA 0.2f

typedef __bf16 bf16x8 __attribute__((ext_vector_type(8)));
typedef __bf16 bf16x4 __attribute__((ext_vector_type(4)));
typedef float f32x4 __attribute__((ext_vector_type(4)));
typedef int i32x4 __attribute__((ext_vector_type(4)));

// ---- workspace layout (bytes) ----
// [0,64)            : Mkey (ordered-uint global max of f_dst)
// [64, 32832)       : lsum (N floats)
// [32832, 65600)    : f_src (N floats)
// [65600, 98368)    : f_dst (N floats)
// [98368, 163904)   : WtG  (bf16 [FOUT][FIN], W transposed)
// [163904, 1212480) : hT   (bf16 [FOUT][N], h transposed)

__device__ __forceinline__ unsigned enc_f(float x) {
    unsigned u = __float_as_uint(x);
    return (u & 0x80000000u) ? ~u : (u | 0x80000000u);
}
__device__ __forceinline__ float dec_f(unsigned u) {
    return (u & 0x80000000u) ? __uint_as_float(u & 0x7FFFFFFFu) : __uint_as_float(~u);
}

// ---------- k_wt: WtG[f][k] = bf16(W[k][f]) --------------------------------
__global__ __launch_bounds__(64) void k_wt(const float* __restrict__ W,
                                           __bf16* __restrict__ WtG) {
    const int g = blockIdx.x * 64 + threadIdx.x;  // 0..4095
    const int k = g >> 3;
    const int f0 = (g & 7) * 8;
    const float4 w0 = *(const float4*)(W + (size_t)k * FOUT + f0);
    const float4 w1 = *(const float4*)(W + (size_t)k * FOUT + f0 + 4);
    WtG[(size_t)(f0 + 0) * FIN + k] = (__bf16)w0.x;
    WtG[(size_t)(f0 + 1) * FIN + k] = (__bf16)w0.y;
    WtG[(size_t)(f0 + 2) * FIN + k] = (__bf16)w0.z;
    WtG[(size_t)(f0 + 3) * FIN + k] = (__bf16)w0.w;
    WtG[(size_t)(f0 + 4) * FIN + k] = (__bf16)w1.x;
    WtG[(size_t)(f0 + 5) * FIN + k] = (__bf16)w1.y;
    WtG[(size_t)(f0 + 6) * FIN + k] = (__bf16)w1.z;
    WtG[(size_t)(f0 + 7) * FIN + k] = (__bf16)w1.w;
}

// ---------- k12: h=in@W (MFMA) -> f_src/f_dst/Mkey + hT (fused) ------------
// 1 wave per block, 16 rows; 512 blocks.
__global__ __launch_bounds__(64) void k12(const float* __restrict__ in,
                                          const __bf16* __restrict__ WtG,
                                          const float* __restrict__ a,
                                          float* __restrict__ f_src,
                                          float* __restrict__ f_dst,
                                          unsigned* __restrict__ Mkey,
                                          __bf16* __restrict__ hT) {
    __shared__ __bf16 tb[64][16];
    const int lane = threadIdx.x;
    const int m = lane & 15, quad = lane >> 4;
    const int i0 = blockIdx.x * 16;

    f32x4 acc[4];
#pragma unroll
    for (int t = 0; t < 4; ++t) acc[t] = (f32x4){0.f, 0.f, 0.f, 0.f};

    const float* arow = in + (size_t)(i0 + m) * FIN + quad * 8;
    for (int k0 = 0; k0 < FIN; k0 += 32) {
        const float4 x0 = *(const float4*)(arow + k0);
        const float4 x1 = *(const float4*)(arow + k0 + 4);
        bf16x8 af;
        af[0] = (__bf16)x0.x; af[1] = (__bf16)x0.y; af[2] = (__bf16)x0.z; af[3] = (__bf16)x0.w;
        af[4] = (__bf16)x1.x; af[5] = (__bf16)x1.y; af[6] = (__bf16)x1.z; af[7] = (__bf16)x1.w;
#pragma unroll
        for (int t = 0; t < 4; ++t) {
            const bf16x8 bf = *(const bf16x8*)(WtG + (size_t)(t * 16 + m) * FIN + k0 + quad * 8);
            acc[t] = __builtin_amdgcn_mfma_f32_16x16x32_bf16(af, bf, acc[t], 0, 0, 0);
        }
    }
    // f_src / f_dst: dot rows with a1/a2, reduce across the 16 m-lanes of each quad
    float s1[4], s2[4];
#pragma unroll
    for (int r = 0; r < 4; ++r) { s1[r] = 0.f; s2[r] = 0.f; }
#pragma unroll
    for (int t = 0; t < 4; ++t) {
        const float a1 = a[t * 16 + m], a2 = a[64 + t * 16 + m];
#pragma unroll
        for (int r = 0; r < 4; ++r) {
            s1[r] += acc[t][r] * a1;
            s2[r] += acc[t][r] * a2;
        }
    }
#pragma unroll
    for (int off = 1; off <= 8; off <<= 1)
#pragma unroll
        for (int r = 0; r < 4; ++r) {
            s1[r] += __shfl_xor(s1[r], off);
            s2[r] += __shfl_xor(s2[r], off);
        }
    float lm = -1e30f;
    if (m == 0) {
#pragma unroll
        for (int r = 0; r < 4; ++r) {
            f_src[i0 + quad * 4 + r] = s1[r];
            f_dst[i0 + quad * 4 + r] = s2[r];
            lm = fmaxf(lm, s2[r]);
        }
    }
    lm = fmaxf(lm, __shfl_xor(lm, 16));
    lm = fmaxf(lm, __shfl_xor(lm, 32));
    if (lane == 0) atomicMax(Mkey, enc_f(lm));

    // hT via LDS transpose, coalesced 16B stores
#pragma unroll
    for (int t = 0; t < 4; ++t)
#pragma unroll
        for (int r = 0; r < 4; ++r) tb[t * 16 + m][quad * 4 + r] = (__bf16)acc[t][r];
    __syncthreads();
    {
        const int f = lane;
        const bf16x8 v0 = *(const bf16x8*)&tb[f][0];
        const bf16x8 v1 = *(const bf16x8*)&tb[f][8];
        *(bf16x8*)(hT + (size_t)f * N + i0) = v0;
        *(bf16x8*)(hT + (size_t)f * N + i0 + 8) = v1;
    }
}

// ---------- k3: fused mask+softmax-weight+PV ------------------------------
// Coalesced adj (row-pairs, 1KB/instr, 8-deep, issued before stage so HBM
// latency hides under staging), hT B-frags from LDS (block-shared), per-wave
// swizzled wl tile bridges coalesced lane layout -> MFMA A-fragment layout.
constexpr int JT = 128;  // j-tile width held in LDS

__global__ __launch_bounds__(256, 4) void k3_attn(const int* __restrict__ adj,
                                                  const float* __restrict__ f_src,
                                                  const float* __restrict__ fdstG,
                                                  const unsigned* __restrict__ Mkey,
                                                  const __bf16* __restrict__ hT,
                                                  float* __restrict__ num,
                                                  float* __restrict__ lsum) {
    __shared__ __bf16 sh[64][JT + 8];   // 17,408 B  (pitch 272B: bank-group spread)
    __shared__ __bf16 wl[4][16][JT];    // 16,384 B  (per-wave, XOR-swizzled)
    __shared__ float sfd[1024];         //  4,096 B
    const int tid = threadIdx.x;
    const int wv = tid >> 6, lane = tid & 63;
    const int m = lane & 15, quad = lane >> 4;
    const int rpar = lane >> 5;          // row parity within pair
    const int col4 = (lane & 31) * 4;    // 4-col chunk owned by this lane
    const int i0 = blockIdx.x * 64 + wv * 16;
    const int jb = blockIdx.y * 1024;
    const float LOG2E = 1.44269504088896f;

    // stage f_dst[jb..jb+1024) cooperatively (visible after first loop barrier)
    *(f32x4*)&sfd[tid * 4] = *(const f32x4*)(fdstG + jb + tid * 4);

    const float M = dec_f(*Mkey);
    float fsr[16], shl[16];  // wave-uniform per-row src-term and shift*LOG2E
#pragma unroll
    for (int r = 0; r < 16; ++r) {
        const float fs = f_src[i0 + r];
        const float t0 = fs + M;
        fsr[r] = fs;
        shl[r] = fmaxf(t0, ALPHA * t0) * LOG2E;  // leaky(fs + max f_dst) * log2(e)
    }

    f32x4 acc[4];
#pragma unroll
    for (int t = 0; t < 4; ++t) acc[t] = (f32x4){0.f, 0.f, 0.f, 0.f};
    f32x4 accl = (f32x4){0.f, 0.f, 0.f, 0.f};

    bf16x8 bones;  // ones-column B: row-sums for the denominator
#pragma unroll
    for (int jj = 0; jj < 8; ++jj) bones[jj] = (__bf16)(m == 0 ? 1.0f : 0.0f);

    const int* apL = adj + (size_t)(i0 + rpar) * N + jb + col4;

    for (int jt = 0; jt < 1024; jt += JT) {
        __syncthreads();  // sh/wl safe to overwrite; first iter: publishes sfd

        // ---- A) adj loads first (coalesced 1KB/instr), latency hides under stage
        i32x4 adjv[8];
#pragma unroll
        for (int v = 0; v < 8; ++v)
            adjv[v] = __builtin_nontemporal_load((const i32x4*)(apL + (size_t)(2 * v) * N + jt));

        // ---- B) stage hT[:, jt:jt+128) (16 KB) cooperatively
#pragma unroll
        for (int it = 0; it < 4; ++it) {
            const int c = tid + it * 256;
            const int f = c >> 4, off = (c & 15) * 8;
            *(bf16x8*)&sh[f][off] = *(const bf16x8*)(hT + (size_t)f * N + jb + jt + off);
        }
        __syncthreads();

        // ---- C) exp-weights -> bf16 -> swizzled per-wave wl tile
        const f32x4 fd = *(const f32x4*)&sfd[jt + col4];
#pragma unroll
        for (int v = 0; v < 8; ++v) {
            const float fs_l = rpar ? fsr[2 * v + 1] : fsr[2 * v];
            const float sh_l = rpar ? shl[2 * v + 1] : shl[2 * v];
            const int rr = 2 * v + rpar;
            bf16x4 wb;
#pragma unroll
            for (int c = 0; c < 4; ++c) {
                float e = fs_l + fd[c];
                e = fmaxf(e, ALPHA * e);
                const float ex = __builtin_amdgcn_exp2f(e * LOG2E - sh_l);
                wb[c] = (__bf16)(adjv[v][c] > 0 ? ex : 0.f);
            }
            *(bf16x4*)&wl[wv][rr][col4 ^ ((rr & 7) << 3)] = wb;
        }

        // ---- D) MFMA: A-frag from wl (swizzled), B-frag from sh
#pragma unroll
        for (int jj0 = 0; jj0 < JT; jj0 += 64) {
#pragma unroll
            for (int u = 0; u < 2; ++u) {
                const int cb = jj0 + u * 32 + quad * 8;
                const bf16x8 af = *(const bf16x8*)&wl[wv][m][cb ^ ((m & 7) << 3)];
#pragma unroll
                for (int t = 0; t < 4; ++t) {
                    const bf16x8 bfr = *(const bf16x8*)&sh[t * 16 + m][cb];
                    acc[t] = __builtin_amdgcn_mfma_f32_16x16x32_bf16(af, bfr, acc[t], 0, 0, 0);
                }
                accl = __builtin_amdgcn_mfma_f32_16x16x32_bf16(af, bones, accl, 0, 0, 0);
            }
        }
    }
    // epilogue: C/D col=lane&15, row=quad*4+reg
#pragma unroll
    for (int t = 0; t < 4; ++t)
#pragma unroll
        for (int r = 0; r < 4; ++r)
            atomicAdd(&num[(size_t)(i0 + quad * 4 + r) * FOUT + t * 16 + m], acc[t][r]);
    if (m == 0) {
#pragma unroll
        for (int r = 0; r < 4; ++r) atomicAdd(&lsum[i0 + quad * 4 + r], accl[r]);
    }
}

// ---------- k4: out = leaky(num / lsum, 0.01) ------------------------------
__global__ __launch_bounds__(256) void k4_norm(float* __restrict__ out,
                                               const float* __restrict__ lsum) {
    const int idx = blockIdx.x * 256 + threadIdx.x;
    const float l = lsum[idx >> 6];
    const float v = out[idx] / (l > 0.f ? l : 1.f);
    out[idx] = v > 0.f ? v : 0.01f * v;
}

extern "C" void kernel_launch(void* const* d_in, const int* in_sizes, int n_in,
                              void* d_out, int out_size, void* d_ws, size_t ws_size,
                              hipStream_t stream) {
    const float* in = (const float*)d_in[0];
    const int* adj = (const int*)d_in[1];
    const float* W = (const float*)d_in[2];
    const float* a = (const float*)d_in[3];
    float* out = (float*)d_out;

    char* ws = (char*)d_ws;
    unsigned* Mkey = (unsigned*)ws;
    float* lsum = (float*)(ws + 64);
    float* f_src = (float*)(ws + 32832);
    float* f_dst = (float*)(ws + 65600);
    __bf16* WtG = (__bf16*)(ws + 98368);
    __bf16* hT = (__bf16*)(ws + 163904);

    hipMemsetAsync(ws, 0, 64 + N * 4, stream);                      // Mkey + lsum
    hipMemsetAsync(d_out, 0, (size_t)N * FOUT * sizeof(float), stream);  // num

    k_wt<<<64, 64, 0, stream>>>(W, WtG);
    k12<<<N / 16, 64, 0, stream>>>(in, WtG, a, f_src, f_dst, Mkey, hT);

    dim3 g3(N / 64, 8);
    k3_attn<<<g3, 256, 0, stream>>>(adj, f_src, f_dst, Mkey, hT, out, lsum);
    k4_norm<<<(N * FOUT) / 256, 256, 0, stream>>>(out, lsum);
}

// Round 4
// 394.762 us; speedup vs baseline: 1.1398x; 1.0063x over previous
//
#include <hip/hip_runtime.h>
#include <hip/hip_bf16.h>

#define N 8192
#define FIN 512
#define FOUT 64
#define ALPHA 0.2f

typedef __bf16 bf16x8 __attribute__((ext_vector_type(8)));
typedef __bf16 bf16x4 __attribute__((ext_vector_type(4)));
typedef float f32x4 __attribute__((ext_vector_type(4)));
typedef int i32x4 __attribute__((ext_vector_type(4)));

// ---- workspace layout (bytes) ----
// [0,64)               : Mkey (ordered-uint global max of f_dst)
// [32832, 65600)       : f_src (N floats)
// [65600, 98368)       : f_dst (N floats)
// [98368, 163904)      : WtG  (bf16 [FOUT][FIN], W transposed)
// [163904, 1212480)    : hT   (bf16 [FOUT][N], h transposed)
// [1212480, 17989696)  : num_part  (f32 [8][N][FOUT], per-y-slice partials)
// [17989696, 18251840) : lsum_part (f32 [8][N])

__device__ __forceinline__ unsigned enc_f(float x) {
    unsigned u = __float_as_uint(x);
    return (u & 0x80000000u) ? ~u : (u | 0x80000000u);
}
__device__ __forceinline__ float dec_f(unsigned u) {
    return (u & 0x80000000u) ? __uint_as_float(u & 0x7FFFFFFFu) : __uint_as_float(~u);
}

// ---------- k_wt: WtG[f][k] = bf16(W[k][f]) --------------------------------
__global__ __launch_bounds__(64) void k_wt(const float* __restrict__ W,
                                           __bf16* __restrict__ WtG) {
    const int g = blockIdx.x * 64 + threadIdx.x;  // 0..4095
    const int k = g >> 3;
    const int f0 = (g & 7) * 8;
    const float4 w0 = *(const float4*)(W + (size_t)k * FOUT + f0);
    const float4 w1 = *(const float4*)(W + (size_t)k * FOUT + f0 + 4);
    WtG[(size_t)(f0 + 0) * FIN + k] = (__bf16)w0.x;
    WtG[(size_t)(f0 + 1) * FIN + k] = (__bf16)w0.y;
    WtG[(size_t)(f0 + 2) * FIN + k] = (__bf16)w0.z;
    WtG[(size_t)(f0 + 3) * FIN + k] = (__bf16)w0.w;
    WtG[(size_t)(f0 + 4) * FIN + k] = (__bf16)w1.x;
    WtG[(size_t)(f0 + 5) * FIN + k] = (__bf16)w1.y;
    WtG[(size_t)(f0 + 6) * FIN + k] = (__bf16)w1.z;
    WtG[(size_t)(f0 + 7) * FIN + k] = (__bf16)w1.w;
}

// ---------- k12: h=in@W (MFMA) -> f_src/f_dst/Mkey + hT (fused) ------------
// 1 wave per block, 16 rows; 512 blocks.
__global__ __launch_bounds__(64) void k12(const float* __restrict__ in,
                                          const __bf16* __restrict__ WtG,
                                          const float* __restrict__ a,
                                          float* __restrict__ f_src,
                                          float* __restrict__ f_dst,
                                          unsigned* __restrict__ Mkey,
                                          __bf16* __restrict__ hT) {
    __shared__ __bf16 tb[64][16];
    const int lane = threadIdx.x;
    const int m = lane & 15, quad = lane >> 4;
    const int i0 = blockIdx.x * 16;

    f32x4 acc[4];
#pragma unroll
    for (int t = 0; t < 4; ++t) acc[t] = (f32x4){0.f, 0.f, 0.f, 0.f};

    const float* arow = in + (size_t)(i0 + m) * FIN + quad * 8;
    for (int k0 = 0; k0 < FIN; k0 += 32) {
        const float4 x0 = *(const float4*)(arow + k0);
        const float4 x1 = *(const float4*)(arow + k0 + 4);
        bf16x8 af;
        af[0] = (__bf16)x0.x; af[1] = (__bf16)x0.y; af[2] = (__bf16)x0.z; af[3] = (__bf16)x0.w;
        af[4] = (__bf16)x1.x; af[5] = (__bf16)x1.y; af[6] = (__bf16)x1.z; af[7] = (__bf16)x1.w;
#pragma unroll
        for (int t = 0; t < 4; ++t) {
            const bf16x8 bf = *(const bf16x8*)(WtG + (size_t)(t * 16 + m) * FIN + k0 + quad * 8);
            acc[t] = __builtin_amdgcn_mfma_f32_16x16x32_bf16(af, bf, acc[t], 0, 0, 0);
        }
    }
    // f_src / f_dst: dot rows with a1/a2, reduce across the 16 m-lanes of each quad
    float s1[4], s2[4];
#pragma unroll
    for (int r = 0; r < 4; ++r) { s1[r] = 0.f; s2[r] = 0.f; }
#pragma unroll
    for (int t = 0; t < 4; ++t) {
        const float a1 = a[t * 16 + m], a2 = a[64 + t * 16 + m];
#pragma unroll
        for (int r = 0; r < 4; ++r) {
            s1[r] += acc[t][r] * a1;
            s2[r] += acc[t][r] * a2;
        }
    }
#pragma unroll
    for (int off = 1; off <= 8; off <<= 1)
#pragma unroll
        for (int r = 0; r < 4; ++r) {
            s1[r] += __shfl_xor(s1[r], off);
            s2[r] += __shfl_xor(s2[r], off);
        }
    float lm = -1e30f;
    if (m == 0) {
#pragma unroll
        for (int r = 0; r < 4; ++r) {
            f_src[i0 + quad * 4 + r] = s1[r];
            f_dst[i0 + quad * 4 + r] = s2[r];
            lm = fmaxf(lm, s2[r]);
        }
    }
    lm = fmaxf(lm, __shfl_xor(lm, 16));
    lm = fmaxf(lm, __shfl_xor(lm, 32));
    if (lane == 0) atomicMax(Mkey, enc_f(lm));

    // hT via LDS transpose, coalesced 16B stores
#pragma unroll
    for (int t = 0; t < 4; ++t)
#pragma unroll
        for (int r = 0; r < 4; ++r) tb[t * 16 + m][quad * 4 + r] = (__bf16)acc[t][r];
    __syncthreads();
    {
        const int f = lane;
        const bf16x8 v0 = *(const bf16x8*)&tb[f][0];
        const bf16x8 v1 = *(const bf16x8*)&tb[f][8];
        *(bf16x8*)(hT + (size_t)f * N + i0) = v0;
        *(bf16x8*)(hT + (size_t)f * N + i0 + 8) = v1;
    }
}

// ---------- k3: fused mask+softmax-weight+PV ------------------------------
// Coalesced adj (row-pairs, 1KB/instr, 8-deep), hT B-frags from LDS, per-wave
// swizzled wl tile bridges coalesced lane layout -> MFMA A-fragment layout.
// Epilogue: plain stores to per-y-slice partial buffers (no atomics).
constexpr int JT = 128;  // j-tile width held in LDS

__global__ __launch_bounds__(256, 4) void k3_attn(const int* __restrict__ adj,
                                                  const float* __restrict__ f_src,
                                                  const float* __restrict__ fdstG,
                                                  const unsigned* __restrict__ Mkey,
                                                  const __bf16* __restrict__ hT,
                                                  float* __restrict__ num_part,
                                                  float* __restrict__ lsum_part) {
    __shared__ __bf16 sh[64][JT + 8];   // 17,408 B  (pitch 272B: bank-group spread)
    __shared__ __bf16 wl[4][16][JT];    // 16,384 B  (per-wave, XOR-swizzled)
    __shared__ float sfd[1024];         //  4,096 B
    const int tid = threadIdx.x;
    const int wv = tid >> 6, lane = tid & 63;
    const int m = lane & 15, quad = lane >> 4;
    const int rpar = lane >> 5;          // row parity within pair
    const int col4 = (lane & 31) * 4;    // 4-col chunk owned by this lane
    const int i0 = blockIdx.x * 64 + wv * 16;
    const int jb = blockIdx.y * 1024;
    const float LOG2E = 1.44269504088896f;

    // stage f_dst[jb..jb+1024) cooperatively (visible after first loop barrier)
    *(f32x4*)&sfd[tid * 4] = *(const f32x4*)(fdstG + jb + tid * 4);

    const float M = dec_f(*Mkey);
    float fsr[16], shl[16];  // wave-uniform per-row src-term and shift*LOG2E
#pragma unroll
    for (int r = 0; r < 16; ++r) {
        const float fs = f_src[i0 + r];
        const float t0 = fs + M;
        fsr[r] = fs;
        shl[r] = fmaxf(t0, ALPHA * t0) * LOG2E;  // leaky(fs + max f_dst) * log2(e)
    }

    f32x4 acc[4];
#pragma unroll
    for (int t = 0; t < 4; ++t) acc[t] = (f32x4){0.f, 0.f, 0.f, 0.f};
    f32x4 accl = (f32x4){0.f, 0.f, 0.f, 0.f};

    bf16x8 bones;  // ones-column B: row-sums for the denominator
#pragma unroll
    for (int jj = 0; jj < 8; ++jj) bones[jj] = (__bf16)(m == 0 ? 1.0f : 0.0f);

    const int* apL = adj + (size_t)(i0 + rpar) * N + jb + col4;

    for (int jt = 0; jt < 1024; jt += JT) {
        __syncthreads();  // sh/wl safe to overwrite; first iter: publishes sfd

        // ---- A) adj loads first (coalesced 1KB/instr), latency hides under stage
        i32x4 adjv[8];
#pragma unroll
        for (int v = 0; v < 8; ++v)
            adjv[v] = __builtin_nontemporal_load((const i32x4*)(apL + (size_t)(2 * v) * N + jt));

        // ---- B) stage hT[:, jt:jt+128) (16 KB) cooperatively
#pragma unroll
        for (int it = 0; it < 4; ++it) {
            const int c = tid + it * 256;
            const int f = c >> 4, off = (c & 15) * 8;
            *(bf16x8*)&sh[f][off] = *(const bf16x8*)(hT + (size_t)f * N + jb + jt + off);
        }
        __syncthreads();

        // ---- C) exp-weights -> bf16 -> swizzled per-wave wl tile
        const f32x4 fd = *(const f32x4*)&sfd[jt + col4];
#pragma unroll
        for (int v = 0; v < 8; ++v) {
            const float fs_l = rpar ? fsr[2 * v + 1] : fsr[2 * v];
            const float sh_l = rpar ? shl[2 * v + 1] : shl[2 * v];
            const int rr = 2 * v + rpar;
            bf16x4 wb;
#pragma unroll
            for (int c = 0; c < 4; ++c) {
                float e = fs_l + fd[c];
                e = fmaxf(e, ALPHA * e);
                const float ex = __builtin_amdgcn_exp2f(e * LOG2E - sh_l);
                wb[c] = (__bf16)(adjv[v][c] > 0 ? ex : 0.f);
            }
            *(bf16x4*)&wl[wv][rr][col4 ^ ((rr & 7) << 3)] = wb;
        }

        // ---- D) MFMA: A-frag from wl (swizzled), B-frag from sh
#pragma unroll
        for (int jj0 = 0; jj0 < JT; jj0 += 64) {
#pragma unroll
            for (int u = 0; u < 2; ++u) {
                const int cb = jj0 + u * 32 + quad * 8;
                const bf16x8 af = *(const bf16x8*)&wl[wv][m][cb ^ ((m & 7) << 3)];
#pragma unroll
                for (int t = 0; t < 4; ++t) {
                    const bf16x8 bfr = *(const bf16x8*)&sh[t * 16 + m][cb];
                    acc[t] = __builtin_amdgcn_mfma_f32_16x16x32_bf16(af, bfr, acc[t], 0, 0, 0);
                }
                accl = __builtin_amdgcn_mfma_f32_16x16x32_bf16(af, bones, accl, 0, 0, 0);
            }
        }
    }
    // epilogue: plain stores to this y-slice's partial buffers (no atomics)
    // C/D layout: col=lane&15, row=quad*4+reg
    float* npb = num_part + (size_t)blockIdx.y * N * FOUT;
#pragma unroll
    for (int t = 0; t < 4; ++t)
#pragma unroll
        for (int r = 0; r < 4; ++r)
            npb[(size_t)(i0 + quad * 4 + r) * FOUT + t * 16 + m] = acc[t][r];
    if (m == 0) {
#pragma unroll
        for (int r = 0; r < 4; ++r)
            lsum_part[(size_t)blockIdx.y * N + i0 + quad * 4 + r] = accl[r];
    }
}

// ---------- k4: out = leaky(sum_p num_part / sum_p lsum_part, 0.01) --------
__global__ __launch_bounds__(256) void k4_norm(float* __restrict__ out,
                                               const float* __restrict__ num_part,
                                               const float* __restrict__ lsum_part) {
    const int idx = blockIdx.x * 256 + threadIdx.x;
    const int i = idx >> 6;
    float s = 0.f, l = 0.f;
#pragma unroll
    for (int p = 0; p < 8; ++p) {
        s += num_part[(size_t)p * N * FOUT + idx];
        l += lsum_part[(size_t)p * N + i];
    }
    const float v = s / (l > 0.f ? l : 1.f);
    out[idx] = v > 0.f ? v : 0.01f * v;
}

extern "C" void kernel_launch(void* const* d_in, const int* in_sizes, int n_in,
                              void* d_out, int out_size, void* d_ws, size_t ws_size,
                              hipStream_t stream) {
    const float* in = (const float*)d_in[0];
    const int* adj = (const int*)d_in[1];
    const float* W = (const float*)d_in[2];
    const float* a = (const float*)d_in[3];
    float* out = (float*)d_out;

    char* ws = (char*)d_ws;
    unsigned* Mkey = (unsigned*)ws;
    float* f_src = (float*)(ws + 32832);
    float* f_dst = (float*)(ws + 65600);
    __bf16* WtG = (__bf16*)(ws + 98368);
    __bf16* hT = (__bf16*)(ws + 163904);
    float* num_part = (float*)(ws + 1212480);
    float* lsum_part = (float*)(ws + 17989696);

    hipMemsetAsync(ws, 0, 64, stream);  // Mkey only

    k_wt<<<64, 64, 0, stream>>>(W, WtG);
    k12<<<N / 16, 64, 0, stream>>>(in, WtG, a, f_src, f_dst, Mkey, hT);

    dim3 g3(N / 64, 8);
    k3_attn<<<g3, 256, 0, stream>>>(adj, f_src, f_dst, Mkey, hT, num_part, lsum_part);
    k4_norm<<<(N * FOUT) / 256, 256, 0, stream>>>(out, num_part, lsum_part);
}

// Round 5
// 390.212 us; speedup vs baseline: 1.1531x; 1.0117x over previous
//
#include <hip/hip_runtime.h>
#include <hip/hip_bf16.h>

#define N 8192
#define FIN 512
#define FOUT 64
#define ALPHA 0.2f

typedef __bf16 bf16x8 __attribute__((ext_vector_type(8)));
typedef __bf16 bf16x4 __attribute__((ext_vector_type(4)));
typedef float f32x4 __attribute__((ext_vector_type(4)));
typedef int i32x4 __attribute__((ext_vector_type(4)));

// ---- workspace layout (bytes) ----
// [0,64)               : Mkey (ordered-uint global max of f_dst)
// [32832, 65600)       : f_src (N floats)
// [65600, 98368)       : f_dst (N floats)
// [98368, 163904)      : WtG  (bf16 [FOUT][FIN], W transposed)
// [163904, 1212480)    : hT   (bf16 [FOUT][N], h transposed)
// [1212480, 17989696)  : num_part  (f32 [8][N][FOUT], per-y-slice partials)
// [17989696, 18251840) : lsum_part (f32 [8][N])

__device__ __forceinline__ unsigned enc_f(float x) {
    unsigned u = __float_as_uint(x);
    return (u & 0x80000000u) ? ~u : (u | 0x80000000u);
}
__device__ __forceinline__ float dec_f(unsigned u) {
    return (u & 0x80000000u) ? __uint_as_float(u & 0x7FFFFFFFu) : __uint_as_float(~u);
}

// async global->LDS, 16B per lane; LDS dest is wave-uniform base + lane*16
__device__ __forceinline__ void glds16(const void* g, void* l) {
    __builtin_amdgcn_global_load_lds((const __attribute__((address_space(1))) void*)g,
                                     (__attribute__((address_space(3))) void*)l, 16, 0, 0);
}
#define SFENCE() __builtin_amdgcn_sched_barrier(0)

// ---------- k_wt: WtG[f][k] = bf16(W[k][f]) --------------------------------
__global__ __launch_bounds__(64) void k_wt(const float* __restrict__ W,
                                           __bf16* __restrict__ WtG) {
    const int g = blockIdx.x * 64 + threadIdx.x;  // 0..4095
    const int k = g >> 3;
    const int f0 = (g & 7) * 8;
    const float4 w0 = *(const float4*)(W + (size_t)k * FOUT + f0);
    const float4 w1 = *(const float4*)(W + (size_t)k * FOUT + f0 + 4);
    WtG[(size_t)(f0 + 0) * FIN + k] = (__bf16)w0.x;
    WtG[(size_t)(f0 + 1) * FIN + k] = (__bf16)w0.y;
    WtG[(size_t)(f0 + 2) * FIN + k] = (__bf16)w0.z;
    WtG[(size_t)(f0 + 3) * FIN + k] = (__bf16)w0.w;
    WtG[(size_t)(f0 + 4) * FIN + k] = (__bf16)w1.x;
    WtG[(size_t)(f0 + 5) * FIN + k] = (__bf16)w1.y;
    WtG[(size_t)(f0 + 6) * FIN + k] = (__bf16)w1.z;
    WtG[(size_t)(f0 + 7) * FIN + k] = (__bf16)w1.w;
}

// ---------- k12: h=in@W (MFMA) -> f_src/f_dst/Mkey + hT (fused) ------------
__global__ __launch_bounds__(64) void k12(const float* __restrict__ in,
                                          const __bf16* __restrict__ WtG,
                                          const float* __restrict__ a,
                                          float* __restrict__ f_src,
                                          float* __restrict__ f_dst,
                                          unsigned* __restrict__ Mkey,
                                          __bf16* __restrict__ hT) {
    __shared__ __bf16 tb[64][16];
    const int lane = threadIdx.x;
    const int m = lane & 15, quad = lane >> 4;
    const int i0 = blockIdx.x * 16;

    f32x4 acc[4];
#pragma unroll
    for (int t = 0; t < 4; ++t) acc[t] = (f32x4){0.f, 0.f, 0.f, 0.f};

    const float* arow = in + (size_t)(i0 + m) * FIN + quad * 8;
    for (int k0 = 0; k0 < FIN; k0 += 32) {
        const float4 x0 = *(const float4*)(arow + k0);
        const float4 x1 = *(const float4*)(arow + k0 + 4);
        bf16x8 af;
        af[0] = (__bf16)x0.x; af[1] = (__bf16)x0.y; af[2] = (__bf16)x0.z; af[3] = (__bf16)x0.w;
        af[4] = (__bf16)x1.x; af[5] = (__bf16)x1.y; af[6] = (__bf16)x1.z; af[7] = (__bf16)x1.w;
#pragma unroll
        for (int t = 0; t < 4; ++t) {
            const bf16x8 bf = *(const bf16x8*)(WtG + (size_t)(t * 16 + m) * FIN + k0 + quad * 8);
            acc[t] = __builtin_amdgcn_mfma_f32_16x16x32_bf16(af, bf, acc[t], 0, 0, 0);
        }
    }
    float s1[4], s2[4];
#pragma unroll
    for (int r = 0; r < 4; ++r) { s1[r] = 0.f; s2[r] = 0.f; }
#pragma unroll
    for (int t = 0; t < 4; ++t) {
        const float a1 = a[t * 16 + m], a2 = a[64 + t * 16 + m];
#pragma unroll
        for (int r = 0; r < 4; ++r) {
            s1[r] += acc[t][r] * a1;
            s2[r] += acc[t][r] * a2;
        }
    }
#pragma unroll
    for (int off = 1; off <= 8; off <<= 1)
#pragma unroll
        for (int r = 0; r < 4; ++r) {
            s1[r] += __shfl_xor(s1[r], off);
            s2[r] += __shfl_xor(s2[r], off);
        }
    float lm = -1e30f;
    if (m == 0) {
#pragma unroll
        for (int r = 0; r < 4; ++r) {
            f_src[i0 + quad * 4 + r] = s1[r];
            f_dst[i0 + quad * 4 + r] = s2[r];
            lm = fmaxf(lm, s2[r]);
        }
    }
    lm = fmaxf(lm, __shfl_xor(lm, 16));
    lm = fmaxf(lm, __shfl_xor(lm, 32));
    if (lane == 0) atomicMax(Mkey, enc_f(lm));

#pragma unroll
    for (int t = 0; t < 4; ++t)
#pragma unroll
        for (int r = 0; r < 4; ++r) tb[t * 16 + m][quad * 4 + r] = (__bf16)acc[t][r];
    __syncthreads();
    {
        const int f = lane;
        const bf16x8 v0 = *(const bf16x8*)&tb[f][0];
        const bf16x8 v1 = *(const bf16x8*)&tb[f][8];
        *(bf16x8*)(hT + (size_t)f * N + i0) = v0;
        *(bf16x8*)(hT + (size_t)f * N + i0 + 8) = v1;
    }
}

// ---------- k3: fused mask+softmax-weight+PV, pipelined (T3/T4) ------------
// Double-buffered sh via global_load_lds (linear dest, pre-swizzled source,
// swizzled read). adj double-buffered in regs one tile ahead. Raw s_barrier
// with counted vmcnt(8) so the 8 adj loads stay in flight across barriers.
constexpr int JT = 128;

__global__ __launch_bounds__(256, 3) void k3_attn(const int* __restrict__ adj,
                                                  const float* __restrict__ f_src,
                                                  const float* __restrict__ fdstG,
                                                  const unsigned* __restrict__ Mkey,
                                                  const __bf16* __restrict__ hT,
                                                  float* __restrict__ num_part,
                                                  float* __restrict__ lsum_part) {
    __shared__ __bf16 sh[2][64][JT];   // 32 KB, linear (glds dest)
    __shared__ __bf16 wl[4][16][JT];   // 16 KB, per-wave, XOR-swizzled
    __shared__ float sfd[1024];        //  4 KB
    const int tid = threadIdx.x;
    const int wv = tid >> 6, lane = tid & 63;
    const int m = lane & 15, quad = lane >> 4;
    const int rpar = lane >> 5;
    const int col4 = (lane & 31) * 4;
    const int i0 = blockIdx.x * 64 + wv * 16;
    const int jb = blockIdx.y * 1024;
    const float LOG2E = 1.44269504088896f;

    // ---- prologue: sfd + wave-uniform row terms; then full drain ----
    *(f32x4*)&sfd[tid * 4] = *(const f32x4*)(fdstG + jb + tid * 4);
    const float M = dec_f(*Mkey);
    float fsr[16], shl[16];
#pragma unroll
    for (int r = 0; r < 16; ++r) {
        const float fs =
            __uint_as_float(__builtin_amdgcn_readfirstlane(__float_as_uint(f_src[i0 + r])));
        const float t0 = fs + M;
        fsr[r] = fs;
        shl[r] = fmaxf(t0, ALPHA * t0) * LOG2E;
    }
    // per-lane glds source pointers (pre-swizzled column)
    const __bf16* gsrc[4];
#pragma unroll
    for (int i = 0; i < 4; ++i) {
        const int f = (wv * 4 + i) * 4 + (lane >> 4);
        const int csw = ((lane & 15) * 8) ^ ((f & 7) << 3);
        gsrc[i] = hT + (size_t)f * N + jb + csw;
    }
    const int* apL = adj + (size_t)(i0 + rpar) * N + jb + col4;

    SFENCE();
    __syncthreads();  // sfd visible; vm queue fully drained (vmcnt==0 here)
    SFENCE();

    f32x4 acc[4];
#pragma unroll
    for (int t = 0; t < 4; ++t) acc[t] = (f32x4){0.f, 0.f, 0.f, 0.f};
    f32x4 accl = (f32x4){0.f, 0.f, 0.f, 0.f};
    bf16x8 bones;
#pragma unroll
    for (int jj = 0; jj < 8; ++jj) bones[jj] = (__bf16)(m == 0 ? 1.0f : 0.0f);

    // ---- pipeline prologue: stage(0) + adj(0) ----
    i32x4 adjv[2][8];
#pragma unroll
    for (int i = 0; i < 4; ++i) glds16(gsrc[i], &sh[0][(wv * 4 + i) * 4][0]);
    SFENCE();
#pragma unroll
    for (int v = 0; v < 8; ++v)
        adjv[0][v] = __builtin_nontemporal_load((const i32x4*)(apL + (size_t)(2 * v) * N));
    SFENCE();
    // queue now: stage(0)[4 oldest] + adj(0)[8]

#pragma unroll
    for (int t = 0; t < 8; ++t) {
        const int jt = t * JT;
        const int cur = t & 1, nxt = cur ^ 1;
        // ---- barrier A: own stage(t) done (adj(t) stays in flight), rendezvous
        asm volatile("s_waitcnt vmcnt(8)" ::: "memory");
        SFENCE();
        __builtin_amdgcn_s_barrier();
        SFENCE();
        // ---- issue stage(t+1) into sh[nxt] (reads of sh[nxt] ended at barrier B(t-1))
        if (t < 7) {
#pragma unroll
            for (int i = 0; i < 4; ++i)
                glds16(gsrc[i] + jt + JT, &sh[nxt][(wv * 4 + i) * 4][0]);
        }
        SFENCE();
        // ---- issue adj(t+1)
        if (t < 7) {
#pragma unroll
            for (int v = 0; v < 8; ++v)
                adjv[nxt][v] = __builtin_nontemporal_load(
                    (const i32x4*)(apL + (size_t)(2 * v) * N + jt + JT));
        }
        SFENCE();
        // ---- C: exp-weights from adjv[cur] -> wl (wave-private, no barrier)
        const f32x4 fd0 = *(const f32x4*)&sfd[jt + col4];
#pragma unroll
        for (int v = 0; v < 8; ++v) {
            const float fs_l = rpar ? fsr[2 * v + 1] : fsr[2 * v];
            const float sh_l = rpar ? shl[2 * v + 1] : shl[2 * v];
            bf16x4 wb;
#pragma unroll
            for (int c = 0; c < 4; ++c) {
                float e = fs_l + fd0[c];
                e = fmaxf(e, ALPHA * e);
                const float ex = __builtin_amdgcn_exp2f(e * LOG2E - sh_l);
                wb[c] = (__bf16)(adjv[cur][v][c] > 0 ? ex : 0.f);
            }
            const int rr = 2 * v + rpar;
            *(bf16x4*)&wl[wv][rr][col4 ^ ((rr & 7) << 3)] = wb;
        }
        SFENCE();
        // ---- D: MFMA; A from wl, B from sh[cur] (swizzled read)
#pragma unroll
        for (int jj0 = 0; jj0 < JT; jj0 += 64) {
#pragma unroll
            for (int u = 0; u < 2; ++u) {
                const int cb = jj0 + u * 32 + quad * 8;
                const int cs = cb ^ ((m & 7) << 3);
                const bf16x8 af = *(const bf16x8*)&wl[wv][m][cs];
#pragma unroll
                for (int tt = 0; tt < 4; ++tt) {
                    const bf16x8 bfr = *(const bf16x8*)&sh[cur][tt * 16 + m][cs];
                    acc[tt] = __builtin_amdgcn_mfma_f32_16x16x32_bf16(af, bfr, acc[tt], 0, 0, 0);
                }
                accl = __builtin_amdgcn_mfma_f32_16x16x32_bf16(af, bones, accl, 0, 0, 0);
            }
        }
        SFENCE();
        // ---- barrier B: all waves done reading sh[cur]
        if (t < 7) {
            asm volatile("s_waitcnt lgkmcnt(0)" ::: "memory");
            SFENCE();
            __builtin_amdgcn_s_barrier();
            SFENCE();
        }
    }
    // epilogue: plain stores to this y-slice's partial buffers
    float* npb = num_part + (size_t)blockIdx.y * N * FOUT;
#pragma unroll
    for (int t = 0; t < 4; ++t)
#pragma unroll
        for (int r = 0; r < 4; ++r)
            npb[(size_t)(i0 + quad * 4 + r) * FOUT + t * 16 + m] = acc[t][r];
    if (m == 0) {
#pragma unroll
        for (int r = 0; r < 4; ++r)
            lsum_part[(size_t)blockIdx.y * N + i0 + quad * 4 + r] = accl[r];
    }
}

// ---------- k4: out = leaky(sum_p num_part / sum_p lsum_part, 0.01) --------
__global__ __launch_bounds__(256) void k4_norm(float* __restrict__ out,
                                               const float* __restrict__ num_part,
                                               const float* __restrict__ lsum_part) {
    const int idx = blockIdx.x * 256 + threadIdx.x;
    const int i = idx >> 6;
    float s = 0.f, l = 0.f;
#pragma unroll
    for (int p = 0; p < 8; ++p) {
        s += num_part[(size_t)p * N * FOUT + idx];
        l += lsum_part[(size_t)p * N + i];
    }
    const float v = s / (l > 0.f ? l : 1.f);
    out[idx] = v > 0.f ? v : 0.01f * v;
}

extern "C" void kernel_launch(void* const* d_in, const int* in_sizes, int n_in,
                              void* d_out, int out_size, void* d_ws, size_t ws_size,
                              hipStream_t stream) {
    const float* in = (const float*)d_in[0];
    const int* adj = (const int*)d_in[1];
    const float* W = (const float*)d_in[2];
    const float* a = (const float*)d_in[3];
    float* out = (float*)d_out;

    char* ws = (char*)d_ws;
    unsigned* Mkey = (unsigned*)ws;
    float* f_src = (float*)(ws + 32832);
    float* f_dst = (float*)(ws + 65600);
    __bf16* WtG = (__bf16*)(ws + 98368);
    __bf16* hT = (__bf16*)(ws + 163904);
    float* num_part = (float*)(ws + 1212480);
    float* lsum_part = (float*)(ws + 17989696);

    hipMemsetAsync(ws, 0, 64, stream);  // Mkey only

    k_wt<<<64, 64, 0, stream>>>(W, WtG);
    k12<<<N / 16, 64, 0, stream>>>(in, WtG, a, f_src, f_dst, Mkey, hT);

    dim3 g3(N / 64, 8);
    k3_attn<<<g3, 256, 0, stream>>>(adj, f_src, f_dst, Mkey, hT, num_part, lsum_part);
    k4_norm<<<(N * FOUT) / 256, 256, 0, stream>>>(out, num_part, lsum_part);
}